// Round 1
// baseline (237.385 us; speedup 1.0000x reference)
//
#include <hip/hip_runtime.h>
#include <stdint.h>

// ---------------------------------------------------------------------------
// WideAndDeep: B=16384, F=3, C=256, D=64, H=1024, ND=13
// deep_in = 205 padded to 224 (7 K-steps of 32 for bf16 MFMA)
// ---------------------------------------------------------------------------

#define BATCH 16384
#define HDIM 1024
#define KPAD 224
#define DEEP_IN 205

typedef short bf16x8 __attribute__((ext_vector_type(8)));
typedef float f32x4 __attribute__((ext_vector_type(4)));

__device__ __forceinline__ float bf2f(uint16_t u) {
    uint32_t x = ((uint32_t)u) << 16;
    float f;
    __builtin_memcpy(&f, &x, 4);
    return f;
}

__device__ __forceinline__ uint16_t f2bf(float f) {
    uint32_t x;
    __builtin_memcpy(&x, &f, 4);
    uint32_t r = (x + 0x7fffu + ((x >> 16) & 1u)) >> 16;
    return (uint16_t)r;
}

__device__ __forceinline__ void async_ld16(const uint16_t* g, uint16_t* l) {
    __builtin_amdgcn_global_load_lds(
        (const __attribute__((address_space(1))) uint32_t*)g,
        (__attribute__((address_space(3))) uint32_t*)l, 16, 0, 0);
}

// ---------------------------------------------------------------------------
// Weight conversion: W1 (1024x205 f32) -> W1b (1024x224 bf16, zero-padded K)
//                    W2 (1024x1024 f32) -> W2b bf16
// ---------------------------------------------------------------------------
__global__ __launch_bounds__(256) void convert_weights(
    const float* __restrict__ W1, const float* __restrict__ W2,
    uint16_t* __restrict__ W1b, uint16_t* __restrict__ W2b)
{
    int idx = blockIdx.x * 256 + threadIdx.x;
    const int W1E = HDIM * KPAD;  // 229376
    if (idx < W1E) {
        int n = idx / KPAD, c = idx - n * KPAD;
        float v = (c < DEEP_IN) ? W1[n * DEEP_IN + c] : 0.f;
        W1b[idx] = f2bf(v);
    } else {
        int k = idx - W1E;
        if (k < HDIM * HDIM) W2b[k] = f2bf(W2[k]);
    }
}

// ---------------------------------------------------------------------------
// deep_x build: [B][224] bf16 = concat(emb[0][s0], emb[1][s1], emb[2][s2],
//                                      dense[13], zeros[19])
// ---------------------------------------------------------------------------
__global__ __launch_bounds__(256) void build_deepx(
    const int* __restrict__ sp, const float* __restrict__ dense,
    const float* __restrict__ emb, uint16_t* __restrict__ dx)
{
    int idx = blockIdx.x * 256 + threadIdx.x;  // < 16384*224
    int b = idx / KPAD, c = idx - b * KPAD;
    float v;
    if (c < 192) {
        int f = c >> 6, cc = c & 63;
        int s = sp[b * 3 + f];
        v = emb[((f << 8) + s) * 64 + cc];
    } else if (c < DEEP_IN) {
        v = dense[b * 13 + (c - 192)];
    } else {
        v = 0.f;
    }
    dx[idx] = f2bf(v);
}

// ---------------------------------------------------------------------------
// Wide path: exact fp32 gathers (replicates reference's cross = cross*F + s)
// ---------------------------------------------------------------------------
__global__ __launch_bounds__(256) void wide_kernel(
    const int* __restrict__ sp, const float* __restrict__ dense,
    const float* __restrict__ ww, const float* __restrict__ wb,
    float* __restrict__ wide)
{
    int b = blockIdx.x * 256 + threadIdx.x;  // < 16384
    int s0 = sp[b * 3], s1 = sp[b * 3 + 1], s2 = sp[b * 3 + 2];
    float w = wb[0];
    w += ww[s0] + ww[256 + s1] + ww[512 + s2];
    w += ww[768    + s0 * 3 + s1];
    w += ww[66304  + s0 * 3 + s2];
    w += ww[131840 + s1 * 3 + s2];
    w += ww[197376 + (s0 * 3 + s1) * 3 + s2];
    const float* wd = ww + 16974592;
    float acc = 0.f;
#pragma unroll
    for (int j = 0; j < 13; j++) acc += dense[b * 13 + j] * wd[j];
    wide[b] = w + acc;
}

// ---------------------------------------------------------------------------
// bf16 GEMM: C[M][N] = act(A[M][K] @ Bw[N][K]^T + bias[N])  (all row-major)
// m97 structure: 128x128 block tile, 4 waves (2x2), each wave 4x4 16x16
// subtiles, global_load_lds(16B), fragment-order LDS (lane-linear ds_read).
// Requires M%128==0, N%128==0, K%32==0, 16B-aligned pointers.
// ---------------------------------------------------------------------------
__global__ __launch_bounds__(256) void gemm_bt(
    const uint16_t* __restrict__ A, const uint16_t* __restrict__ Bw,
    const float* __restrict__ bias, uint16_t* __restrict__ C,
    int M, int N, int K, int relu)
{
    __shared__ __align__(16) uint16_t Al[4096];  // 128x32, fragment order
    __shared__ __align__(16) uint16_t Bl[4096];

    const int tid = threadIdx.x;
    const int lane = tid & 63;
    const int wave = tid >> 6;
    const int wm = wave >> 1, wn = wave & 1;
    const int bm = blockIdx.y * 128;
    const int bn = blockIdx.x * 128;
    const int rl = lane & 15, q = lane >> 4;

    f32x4 acc[4][4];
#pragma unroll
    for (int i = 0; i < 4; i++)
#pragma unroll
        for (int j = 0; j < 4; j++) acc[i][j] = (f32x4)0.f;

    // Each wave stages chunks 2w, 2w+1 of both tiles. Chunk c covers rows
    // [c*16, c*16+16) of the tile; lane l loads row rl=l&15, k-offset (l>>4)*8,
    // landing at LDS chunk base + l*16B (fragment order).
    const int c0 = wave * 2, c1 = wave * 2 + 1;
    const uint16_t* a_src0 = A + (size_t)(bm + c0 * 16 + rl) * K + q * 8;
    const uint16_t* a_src1 = A + (size_t)(bm + c1 * 16 + rl) * K + q * 8;
    const uint16_t* b_src0 = Bw + (size_t)(bn + c0 * 16 + rl) * K + q * 8;
    const uint16_t* b_src1 = Bw + (size_t)(bn + c1 * 16 + rl) * K + q * 8;
    uint16_t* a_dst0 = &Al[c0 * 512];
    uint16_t* a_dst1 = &Al[c1 * 512];
    uint16_t* b_dst0 = &Bl[c0 * 512];
    uint16_t* b_dst1 = &Bl[c1 * 512];

    for (int k0 = 0; k0 < K; k0 += 32) {
        __syncthreads();  // previous iteration's LDS reads done
        async_ld16(a_src0 + k0, a_dst0);
        async_ld16(a_src1 + k0, a_dst1);
        async_ld16(b_src0 + k0, b_dst0);
        async_ld16(b_src1 + k0, b_dst1);
        asm volatile("s_waitcnt vmcnt(0)" ::: "memory");
        __syncthreads();

        bf16x8 af[4], bfr[4];
#pragma unroll
        for (int i = 0; i < 4; i++)
            af[i] = *(const bf16x8*)&Al[(wm * 4 + i) * 512 + lane * 8];
#pragma unroll
        for (int j = 0; j < 4; j++)
            bfr[j] = *(const bf16x8*)&Bl[(wn * 4 + j) * 512 + lane * 8];
#pragma unroll
        for (int i = 0; i < 4; i++)
#pragma unroll
            for (int j = 0; j < 4; j++)
                acc[i][j] = __builtin_amdgcn_mfma_f32_16x16x32_bf16(
                    af[i], bfr[j], acc[i][j], 0, 0, 0);
    }

    // Epilogue: C/D layout col = lane&15, row = (lane>>4)*4 + reg
#pragma unroll
    for (int i = 0; i < 4; i++) {
#pragma unroll
        for (int j = 0; j < 4; j++) {
            int n = bn + (wn * 4 + j) * 16 + rl;
            float bv = bias[n];
#pragma unroll
            for (int r = 0; r < 4; r++) {
                int m = bm + (wm * 4 + i) * 16 + q * 4 + r;
                float v = acc[i][j][r] + bv;
                if (relu) v = fmaxf(v, 0.f);
                C[(size_t)m * N + n] = f2bf(v);
            }
        }
    }
}

// ---------------------------------------------------------------------------
// Final: out[b] = sigmoid(wide[b] + h2[b] . W3 + b3); one wave per row.
// ---------------------------------------------------------------------------
typedef uint16_t u16x8 __attribute__((ext_vector_type(8)));

__global__ __launch_bounds__(256) void final_kernel(
    const uint16_t* __restrict__ h2, const float* __restrict__ W3,
    const float* __restrict__ b3, const float* __restrict__ wide,
    float* __restrict__ out)
{
    int wave = threadIdx.x >> 6, lane = threadIdx.x & 63;
    int row = blockIdx.x * 4 + wave;  // grid 4096
    const uint16_t* hr = h2 + (size_t)row * HDIM + lane * 16;
    u16x8 h0 = *(const u16x8*)hr;
    u16x8 h1 = *(const u16x8*)(hr + 8);
    const float* w3 = W3 + lane * 16;
    float s = 0.f;
#pragma unroll
    for (int t = 0; t < 8; t++) s += bf2f(h0[t]) * w3[t];
#pragma unroll
    for (int t = 0; t < 8; t++) s += bf2f(h1[t]) * w3[8 + t];
#pragma unroll
    for (int off = 32; off; off >>= 1) s += __shfl_down(s, off, 64);
    if (lane == 0) {
        float x = s + wide[row] + b3[0];
        out[row] = 1.f / (1.f + __expf(-x));
    }
}

// ---------------------------------------------------------------------------
extern "C" void kernel_launch(void* const* d_in, const int* in_sizes, int n_in,
                              void* d_out, int out_size, void* d_ws, size_t ws_size,
                              hipStream_t stream) {
    const int*   sp    = (const int*)d_in[0];
    const float* dense = (const float*)d_in[1];
    const float* ww    = (const float*)d_in[2];
    const float* wb    = (const float*)d_in[3];
    const float* emb   = (const float*)d_in[4];
    const float* W1    = (const float*)d_in[5];
    const float* b1    = (const float*)d_in[6];
    const float* W2    = (const float*)d_in[7];
    const float* b2    = (const float*)d_in[8];
    const float* W3    = (const float*)d_in[9];
    const float* b3    = (const float*)d_in[10];
    float* out = (float*)d_out;

    char* ws = (char*)d_ws;
    float*    wide = (float*)ws;                       //     65,536 B
    uint16_t* dxp  = (uint16_t*)(ws + 65536);          //  7,340,032 B
    uint16_t* W1b  = (uint16_t*)(ws + 7405568);        //    458,752 B
    uint16_t* W2b  = (uint16_t*)(ws + 7864320);        //  2,097,152 B
    uint16_t* h1   = (uint16_t*)(ws + 9961472);        // 33,554,432 B
    uint16_t* h2   = (uint16_t*)(ws + 43515904);       // 33,554,432 B -> 77,070,336 total

    convert_weights<<<4992, 256, 0, stream>>>(W1, W2, W1b, W2b);
    build_deepx<<<14336, 256, 0, stream>>>(sp, dense, emb, dxp);
    wide_kernel<<<64, 256, 0, stream>>>(sp, dense, ww, wb, wide);
    gemm_bt<<<dim3(HDIM / 128, BATCH / 128), 256, 0, stream>>>(
        dxp, W1b, b1, h1, BATCH, HDIM, KPAD, 1);
    gemm_bt<<<dim3(HDIM / 128, BATCH / 128), 256, 0, stream>>>(
        h1, W2b, b2, h2, BATCH, HDIM, HDIM, 1);
    final_kernel<<<BATCH / 4, 256, 0, stream>>>(h2, W3, b3, wide, out);
}

// Round 2
// 226.738 us; speedup vs baseline: 1.0470x; 1.0470x over previous
//
#include <hip/hip_runtime.h>
#include <stdint.h>

// ---------------------------------------------------------------------------
// WideAndDeep: B=16384, F=3, C=256, D=64, H=1024, ND=13
// deep_in = 205 padded to 256 (4 K-steps of 64 for bf16 MFMA, BK=64)
// ---------------------------------------------------------------------------

#define BATCH 16384
#define HDIM 1024
#define KPAD 256
#define DEEP_IN 205

typedef short bf16x8 __attribute__((ext_vector_type(8)));
typedef float f32x4 __attribute__((ext_vector_type(4)));

__device__ __forceinline__ float bf2f(uint16_t u) {
    uint32_t x = ((uint32_t)u) << 16;
    float f;
    __builtin_memcpy(&f, &x, 4);
    return f;
}

__device__ __forceinline__ uint16_t f2bf(float f) {
    uint32_t x;
    __builtin_memcpy(&x, &f, 4);
    uint32_t r = (x + 0x7fffu + ((x >> 16) & 1u)) >> 16;
    return (uint16_t)r;
}

__device__ __forceinline__ void async_ld16(const uint16_t* g, uint16_t* l) {
    __builtin_amdgcn_global_load_lds(
        (const __attribute__((address_space(1))) uint32_t*)g,
        (__attribute__((address_space(3))) uint32_t*)l, 16, 0, 0);
}

// ---------------------------------------------------------------------------
// Weight conversion: W1 (1024x205 f32) -> W1b (1024x256 bf16, zero-padded K)
//                    W2 (1024x1024 f32) -> W2b bf16
// ---------------------------------------------------------------------------
__global__ __launch_bounds__(256) void convert_weights(
    const float* __restrict__ W1, const float* __restrict__ W2,
    uint16_t* __restrict__ W1b, uint16_t* __restrict__ W2b)
{
    int idx = blockIdx.x * 256 + threadIdx.x;
    const int W1E = HDIM * KPAD;  // 262144
    if (idx < W1E) {
        int n = idx >> 8, c = idx & 255;
        float v = (c < DEEP_IN) ? W1[n * DEEP_IN + c] : 0.f;
        W1b[idx] = f2bf(v);
    } else {
        int k = idx - W1E;
        if (k < HDIM * HDIM) W2b[k] = f2bf(W2[k]);
    }
}

// ---------------------------------------------------------------------------
// deep_x build: [B][256] bf16 = concat(emb[0][s0], emb[1][s1], emb[2][s2],
//                                      dense[13], zeros[51])
// ---------------------------------------------------------------------------
__global__ __launch_bounds__(256) void build_deepx(
    const int* __restrict__ sp, const float* __restrict__ dense,
    const float* __restrict__ emb, uint16_t* __restrict__ dx)
{
    int idx = blockIdx.x * 256 + threadIdx.x;  // < 16384*256
    int b = idx >> 8, c = idx & 255;
    float v;
    if (c < 192) {
        int f = c >> 6, cc = c & 63;
        int s = sp[b * 3 + f];
        v = emb[((f << 8) + s) * 64 + cc];
    } else if (c < DEEP_IN) {
        v = dense[b * 13 + (c - 192)];
    } else {
        v = 0.f;
    }
    dx[idx] = f2bf(v);
}

// ---------------------------------------------------------------------------
// Wide path: exact fp32 gathers (replicates reference's cross = cross*F + s)
// ---------------------------------------------------------------------------
__global__ __launch_bounds__(256) void wide_kernel(
    const int* __restrict__ sp, const float* __restrict__ dense,
    const float* __restrict__ ww, const float* __restrict__ wb,
    float* __restrict__ wide)
{
    int b = blockIdx.x * 256 + threadIdx.x;  // < 16384
    int s0 = sp[b * 3], s1 = sp[b * 3 + 1], s2 = sp[b * 3 + 2];
    float w = wb[0];
    w += ww[s0] + ww[256 + s1] + ww[512 + s2];
    w += ww[768    + s0 * 3 + s1];
    w += ww[66304  + s0 * 3 + s2];
    w += ww[131840 + s1 * 3 + s2];
    w += ww[197376 + (s0 * 3 + s1) * 3 + s2];
    const float* wd = ww + 16974592;
    float acc = 0.f;
#pragma unroll
    for (int j = 0; j < 13; j++) acc += dense[b * 13 + j] * wd[j];
    wide[b] = w + acc;
}

// ---------------------------------------------------------------------------
// bf16 GEMM: C[M][N] = act(A[M][K] @ Bw[N][K]^T + bias[N])  (all row-major)
// 128x128 block tile, BK=64, 4 waves (2x2), each wave 4x4 16x16 subtiles,
// global_load_lds(16B), fragment-order LDS (lane-linear ds_read).
// Requires M%128==0, N==1024 (swizzle hardcodes nx=8), K%64==0, 16B-aligned.
// 1D grid of (M/128)*8 blocks; XCD swizzle: all 8 n-blocks of one m-band land
// on the same XCD (id%8) so the A-tile is L2-resident across its 8 sharers.
// ---------------------------------------------------------------------------
__global__ __launch_bounds__(256) void gemm_bt(
    const uint16_t* __restrict__ A, const uint16_t* __restrict__ Bw,
    const float* __restrict__ bias, uint16_t* __restrict__ C,
    int M, int N, int K, int relu)
{
    __shared__ __align__(16) uint16_t Al[8192];  // 128x64, fragment order
    __shared__ __align__(16) uint16_t Bl[8192];

    const int tid = threadIdx.x;
    const int lane = tid & 63;
    const int wave = tid >> 6;
    const int wm = wave >> 1, wn = wave & 1;

    // XCD-aware swizzle (assumes round-robin id%8 -> XCD):
    // XCD j owns m-bands [j*MB8, (j+1)*MB8); within, n fastest.
    const int id = blockIdx.x;
    const int xcd = id & 7;
    const int slot = id >> 3;
    const int mb8 = (M >> 7) >> 3;          // m-bands per XCD
    const int by = xcd * mb8 + (slot >> 3); // m-band
    const int bx = slot & 7;                // n-band (nx = 8)
    const int bm = by * 128;
    const int bn = bx * 128;
    const int rl = lane & 15, q = lane >> 4;

    f32x4 acc[4][4];
#pragma unroll
    for (int i = 0; i < 4; i++)
#pragma unroll
        for (int j = 0; j < 4; j++) acc[i][j] = (f32x4)0.f;

    // Staging, fragment order. Chunk c (16 rows), k-half kh: LDS base
    // c*1024 + kh*512; lane l lands at +l*8 elems = row l&15, k kh*32+(l>>4)*8.
    // Wave w stages chunks 2w, 2w+1 (both kh) of A and B: 8 async ops/wave.
    const int c0 = wave * 2, c1 = wave * 2 + 1;
    const uint16_t* aS0 = A + (size_t)(bm + c0 * 16 + rl) * K + q * 8;
    const uint16_t* aS1 = A + (size_t)(bm + c1 * 16 + rl) * K + q * 8;
    const uint16_t* bS0 = Bw + (size_t)(bn + c0 * 16 + rl) * K + q * 8;
    const uint16_t* bS1 = Bw + (size_t)(bn + c1 * 16 + rl) * K + q * 8;
    uint16_t* aD0 = &Al[c0 * 1024];
    uint16_t* aD1 = &Al[c1 * 1024];
    uint16_t* bD0 = &Bl[c0 * 1024];
    uint16_t* bD1 = &Bl[c1 * 1024];

    for (int k0 = 0; k0 < K; k0 += 64) {
        __syncthreads();  // previous iteration's LDS reads done
        async_ld16(aS0 + k0,      aD0);
        async_ld16(aS0 + k0 + 32, aD0 + 512);
        async_ld16(aS1 + k0,      aD1);
        async_ld16(aS1 + k0 + 32, aD1 + 512);
        async_ld16(bS0 + k0,      bD0);
        async_ld16(bS0 + k0 + 32, bD0 + 512);
        async_ld16(bS1 + k0,      bD1);
        async_ld16(bS1 + k0 + 32, bD1 + 512);
        asm volatile("s_waitcnt vmcnt(0)" ::: "memory");
        __syncthreads();

#pragma unroll
        for (int kh = 0; kh < 2; kh++) {
            bf16x8 af[4], bfr[4];
#pragma unroll
            for (int i = 0; i < 4; i++)
                af[i] = *(const bf16x8*)&Al[(wm * 4 + i) * 1024 + kh * 512 + lane * 8];
#pragma unroll
            for (int j = 0; j < 4; j++)
                bfr[j] = *(const bf16x8*)&Bl[(wn * 4 + j) * 1024 + kh * 512 + lane * 8];
#pragma unroll
            for (int i = 0; i < 4; i++)
#pragma unroll
                for (int j = 0; j < 4; j++)
                    acc[i][j] = __builtin_amdgcn_mfma_f32_16x16x32_bf16(
                        af[i], bfr[j], acc[i][j], 0, 0, 0);
        }
    }

    // Epilogue: C/D layout col = lane&15, row = (lane>>4)*4 + reg
#pragma unroll
    for (int i = 0; i < 4; i++) {
#pragma unroll
        for (int j = 0; j < 4; j++) {
            int n = bn + (wn * 4 + j) * 16 + rl;
            float bv = bias[n];
#pragma unroll
            for (int r = 0; r < 4; r++) {
                int m = bm + (wm * 4 + i) * 16 + q * 4 + r;
                float v = acc[i][j][r] + bv;
                if (relu) v = fmaxf(v, 0.f);
                C[(size_t)m * N + n] = f2bf(v);
            }
        }
    }
}

// ---------------------------------------------------------------------------
// Final: out[b] = sigmoid(wide[b] + h2[b] . W3 + b3); one wave per row.
// ---------------------------------------------------------------------------
typedef uint16_t u16x8 __attribute__((ext_vector_type(8)));

__global__ __launch_bounds__(256) void final_kernel(
    const uint16_t* __restrict__ h2, const float* __restrict__ W3,
    const float* __restrict__ b3, const float* __restrict__ wide,
    float* __restrict__ out)
{
    int wave = threadIdx.x >> 6, lane = threadIdx.x & 63;
    int row = blockIdx.x * 4 + wave;  // grid 4096
    const uint16_t* hr = h2 + (size_t)row * HDIM + lane * 16;
    u16x8 h0 = *(const u16x8*)hr;
    u16x8 h1 = *(const u16x8*)(hr + 8);
    const float* w3 = W3 + lane * 16;
    float s = 0.f;
#pragma unroll
    for (int t = 0; t < 8; t++) s += bf2f(h0[t]) * w3[t];
#pragma unroll
    for (int t = 0; t < 8; t++) s += bf2f(h1[t]) * w3[8 + t];
#pragma unroll
    for (int off = 32; off; off >>= 1) s += __shfl_down(s, off, 64);
    if (lane == 0) {
        float x = s + wide[row] + b3[0];
        out[row] = 1.f / (1.f + __expf(-x));
    }
}

// ---------------------------------------------------------------------------
extern "C" void kernel_launch(void* const* d_in, const int* in_sizes, int n_in,
                              void* d_out, int out_size, void* d_ws, size_t ws_size,
                              hipStream_t stream) {
    const int*   sp    = (const int*)d_in[0];
    const float* dense = (const float*)d_in[1];
    const float* ww    = (const float*)d_in[2];
    const float* wb    = (const float*)d_in[3];
    const float* emb   = (const float*)d_in[4];
    const float* W1    = (const float*)d_in[5];
    const float* b1    = (const float*)d_in[6];
    const float* W2    = (const float*)d_in[7];
    const float* b2    = (const float*)d_in[8];
    const float* W3    = (const float*)d_in[9];
    const float* b3    = (const float*)d_in[10];
    float* out = (float*)d_out;

    char* ws = (char*)d_ws;
    float*    wide = (float*)ws;                       //     65,536 B
    uint16_t* dxp  = (uint16_t*)(ws + 65536);          //  8,388,608 B
    uint16_t* W1b  = (uint16_t*)(ws + 8454144);        //    524,288 B
    uint16_t* W2b  = (uint16_t*)(ws + 8978432);        //  2,097,152 B
    uint16_t* h1   = (uint16_t*)(ws + 11075584);       // 33,554,432 B
    uint16_t* h2   = (uint16_t*)(ws + 44630016);       // 33,554,432 B -> 78,184,448 total

    convert_weights<<<5120, 256, 0, stream>>>(W1, W2, W1b, W2b);
    build_deepx<<<16384, 256, 0, stream>>>(sp, dense, emb, dxp);
    wide_kernel<<<64, 256, 0, stream>>>(sp, dense, ww, wb, wide);
    gemm_bt<<<(BATCH / 128) * 8, 256, 0, stream>>>(
        dxp, W1b, b1, h1, BATCH, HDIM, KPAD, 1);
    gemm_bt<<<(BATCH / 128) * 8, 256, 0, stream>>>(
        h1, W2b, b2, h2, BATCH, HDIM, HDIM, 1);
    final_kernel<<<BATCH / 4, 256, 0, stream>>>(h2, W3, b3, wide, out);
}